// Round 1
// 921.743 us; speedup vs baseline: 1.0592x; 1.0592x over previous
//
#include <hip/hip_runtime.h>
#include <hip/hip_bf16.h>

typedef unsigned short u16;
typedef unsigned int u32;
typedef __attribute__((ext_vector_type(8))) short short8;
typedef __attribute__((ext_vector_type(4))) float floatx4;

__device__ __forceinline__ u16 f2bf(float f) {
  u32 x = __float_as_uint(f);
  x += 0x7FFFu + ((x >> 16) & 1u);
  return (u16)(x >> 16);
}
__device__ __forceinline__ u32 pk2(float lo, float hi) {
  return (u32)f2bf(lo) | ((u32)f2bf(hi) << 16);
}

// ---------------- embedding gather: x[tok][d] = emb[ids[tok]][d] ----
__global__ void embed_kernel(const int* __restrict__ ids, const float* __restrict__ emb,
                             float* __restrict__ x) {
  int tok = blockIdx.x, d = threadIdx.x;
  x[tok * 256 + d] = emb[(size_t)ids[tok] * 256 + d];
}

// ---------------- bf16 MFMA GEMM: C = act(A[M,K] @ W[N,K]^T + bias) ------------
// block 256 (4 waves), tile 64x64, K-step 32, DOUBLE-BUFFERED LDS with register
// prefetch: per K-step only ONE barrier (write buf -> prefetch next -> barrier ->
// read buf). fp32 inputs converted to bf16 in staging, fp32 MFMA accumulate.
// Wave w owns rows w*16..w*16+15, all 4 16-col tiles.
// SPLIT=1: write partial sums to C + kz*pstride (no bias/act).
// DUAL mode: n-tiles with n0 >= nsplit switch to {Wb, biasb, Cb, A+koffb} so two
// independent GEMMs sharing M/K geometry run in one launch (decoder A/B merge).
// A-frag: lane holds A[m=lane&15][k=(lane>>4)*8+j]; B-frag same pattern on W.
// C/D: col=lane&15, row=(lane>>4)*4+reg  [guide §3, m89/m91].
template <int ACT, int SPLIT>
__global__ __launch_bounds__(256) void mfma_gemm_kernel(
    const float* __restrict__ A, int lda,
    const float* __restrict__ Wa, const float* __restrict__ Wb, int nsplit, int koffb,
    const float* __restrict__ biasa, const float* __restrict__ biasb,
    float* __restrict__ Ca, float* __restrict__ Cb,
    int N, int K, int KS, int pstride) {
  __shared__ u16 Abf[2][64 * 32];
  __shared__ u16 Wbf[2][64 * 32];
  const int t = threadIdx.x;
  const int m0 = blockIdx.x * 64;
  int n0 = blockIdx.y * 64;
  const int kz = blockIdx.z;
  const float* W = Wa;
  const float* bias = biasa;
  const float* Ain = A;
  float* C = Ca;
  if (n0 >= nsplit) { n0 -= nsplit; W = Wb; bias = biasb; C = Cb; Ain = A + koffb; }
  const int srow = t >> 2, skc = (t & 3) * 8;   // staging: row 0..63, k-chunk 0/8/16/24
  const int w = t >> 6, lane = t & 63;
  const int q = lane >> 4, rr = lane & 15;
  floatx4 acc[4];
#pragma unroll
  for (int i = 0; i < 4; ++i) acc[i] = (floatx4){0.f, 0.f, 0.f, 0.f};

  const int kbeg = kz * KS, kend = kbeg + KS;
  const float* ga = Ain + (size_t)(m0 + srow) * lda + kbeg + skc;
  const float* gw = W + (size_t)(n0 + srow) * K + kbeg + skc;
  float4 a0 = *(const float4*)ga;
  float4 a1 = *(const float4*)(ga + 4);
  float4 w0 = *(const float4*)gw;
  float4 w1 = *(const float4*)(gw + 4);
  int buf = 0;
  for (int k0 = kbeg; k0 < kend; k0 += 32) {
    uint4 pa, pw;
    pa.x = pk2(a0.x, a0.y); pa.y = pk2(a0.z, a0.w);
    pa.z = pk2(a1.x, a1.y); pa.w = pk2(a1.z, a1.w);
    pw.x = pk2(w0.x, w0.y); pw.y = pk2(w0.z, w0.w);
    pw.z = pk2(w1.x, w1.y); pw.w = pk2(w1.z, w1.w);
    // staging layout is linear in t: u16 index t*8 == srow*32 + skc
    *(uint4*)&Abf[buf][t * 8] = pa;
    *(uint4*)&Wbf[buf][t * 8] = pw;
    if (k0 + 32 < kend) {          // prefetch next K-step; latency hides under MFMA
      ga += 32; gw += 32;
      a0 = *(const float4*)ga;
      a1 = *(const float4*)(ga + 4);
      w0 = *(const float4*)gw;
      w1 = *(const float4*)(gw + 4);
    }
    __syncthreads();               // single barrier: writes of buf visible before reads
    short8 af = *(short8*)&Abf[buf][(w * 16 + rr) * 32 + q * 8];
#pragma unroll
    for (int ct = 0; ct < 4; ++ct) {
      short8 bfv = *(short8*)&Wbf[buf][(ct * 16 + rr) * 32 + q * 8];
      acc[ct] = __builtin_amdgcn_mfma_f32_16x16x32_bf16(af, bfv, acc[ct], 0, 0, 0);
    }
    buf ^= 1;                      // next write goes to other buffer (no 2nd barrier)
  }

  float* dst = SPLIT ? (C + (size_t)kz * pstride) : C;
#pragma unroll
  for (int ct = 0; ct < 4; ++ct) {
    int col = n0 + ct * 16 + rr;
#pragma unroll
    for (int r = 0; r < 4; ++r) {
      int row = m0 + w * 16 + q * 4 + r;
      float v = acc[ct][r];
      if (!SPLIT) {
        v += bias[col];
        if (ACT == 1) v = fmaxf(v, 0.f);
        if (ACT == 2) v = 0.5f * v * (1.f + erff(v * 0.70710678118654752f));
      }
      dst[(size_t)row * N + col] = v;
    }
  }
}

// ---------------- fused decoder stage-1 reduce: h[row][{A:0..255,B:256..511}] ----
// blocks 0..895 -> A half (partsA, a1_b), 896..1791 -> B half (partsB, b1_b).
// GELU applied here; h row stride 512 so stage-2 dual GEMM reads either half.
__global__ __launch_bounds__(256) void red_gelu_dual_kernel(const float* __restrict__ pa,
    const float* __restrict__ pb, const float* __restrict__ ba, const float* __restrict__ bb,
    float* __restrict__ h) {
  int blk = blockIdx.x;
  int second = blk >= 896;
  int row = second ? blk - 896 : blk;
  const float* parts = second ? pb : pa;
  const float* bias = second ? bb : ba;
  int c = threadIdx.x;
  float v = bias[c];
#pragma unroll
  for (int p = 0; p < 4; ++p) v += parts[(size_t)p * 229376 + row * 256 + c];
  v = 0.5f * v * (1.f + erff(v * 0.70710678118654752f));
  h[(size_t)row * 512 + second * 256 + c] = v;
}

// ---------------- attention: one wave per query; K xor-swizzled in LDS ---------
// V is NOT staged: qkv (1.5 MB) is L2-resident and PV reads are lane-contiguous,
// so LDS staging of V was pure overhead (and halved occupancy: 64KB->32KB LDS).
__global__ __launch_bounds__(256) void attn_kernel(const float* __restrict__ qkv,
    const int* __restrict__ mask, float* __restrict__ o) {
  __shared__ float Klds[8192];
  const int blk = blockIdx.x;                 // 512 = 4b * 4h * 32 qgroups
  const int b = blk >> 7, h = (blk >> 5) & 3, qg = blk & 31;
  const int t = threadIdx.x;
  for (int i = t; i < 8192; i += 256) {
    int s = i >> 6, d = i & 63;
    Klds[(s << 6) + (d ^ (s & 31))] = qkv[(size_t)(b * 128 + s) * 768 + h * 64 + 256 + d];
  }
  __syncthreads();
  const int wave = t >> 6, lane = t & 63;
  const int q = qg * 4 + wave;
  float qv = qkv[(size_t)(b * 128 + q) * 768 + h * 64 + lane];
  const int m0i = mask[b * 128 + lane];
  const int m1i = mask[b * 128 + 64 + lane];
  float s0 = 0.f, s1 = 0.f;
  const int sw = lane & 31;
  for (int d = 0; d < 64; ++d) {
    float qd = __shfl(qv, d);
    s0 += qd * Klds[(lane << 6) + (d ^ sw)];
    s1 += qd * Klds[((lane + 64) << 6) + (d ^ sw)];
  }
  s0 *= 0.125f; s1 *= 0.125f;
  if (m0i == 0) s0 = -1000000000.0f;
  if (m1i == 0) s1 = -1000000000.0f;
  float m = fmaxf(s0, s1);
  for (int off = 32; off; off >>= 1) m = fmaxf(m, __shfl_xor(m, off));
  float p0 = expf(s0 - m), p1 = expf(s1 - m);
  float sum = p0 + p1;
  for (int off = 32; off; off >>= 1) sum += __shfl_xor(sum, off);
  float rs = 1.f / sum;
  const float* vb = qkv + (size_t)b * 98304 + h * 64 + 512 + lane;
  float acc = 0.f;
#pragma unroll
  for (int k = 0; k < 64; ++k) acc += __shfl(p0, k) * vb[(size_t)k * 768];
#pragma unroll
  for (int k = 0; k < 64; ++k) acc += __shfl(p1, k) * vb[(size_t)(k + 64) * 768];
  o[(size_t)(b * 128 + q) * 256 + h * 64 + lane] = acc * rs;
}

// ---------------- residual + split-K reduce + bias + LayerNorm (in-place on x) ----
__global__ __launch_bounds__(256) void add_ln_red_kernel(float* __restrict__ x,
    const float* __restrict__ parts, int nparts, int pstride, const float* __restrict__ bias,
    const float* __restrict__ g, const float* __restrict__ b) {
  int tok = blockIdx.x, t = threadIdx.x;
  int idx = tok * 256 + t;
  float r = x[idx] + bias[t];
  for (int p = 0; p < nparts; ++p) r += parts[(size_t)p * pstride + idx];
  float s = r, sq = r * r;
  for (int off = 32; off; off >>= 1) { s += __shfl_xor(s, off); sq += __shfl_xor(sq, off); }
  __shared__ float red[8];
  int wave = t >> 6, lane = t & 63;
  if (lane == 0) { red[wave] = s; red[4 + wave] = sq; }
  __syncthreads();
  float S = red[0] + red[1] + red[2] + red[3];
  float SQ = red[4] + red[5] + red[6] + red[7];
  float mean = S * (1.f / 256.f);
  float var = SQ * (1.f / 256.f) - mean * mean;
  float inv = 1.f / sqrtf(fmaxf(var, 0.f) + 1e-5f);
  x[idx] = (r - mean) * inv * g[t] + b[t];
}

// ---------------- masked mean pool -> pooled[4][256] ----------------
__global__ void pool_kernel(const float* __restrict__ x, const int* __restrict__ mask,
                            float* __restrict__ pooled) {
  int b = blockIdx.x, d = threadIdx.x;
  float s = 0.f, c = 0.f;
  for (int ss = 0; ss < 128; ++ss) {
    float m = (float)mask[b * 128 + ss];
    s += m * x[(size_t)(b * 128 + ss) * 256 + d];
    c += m;
  }
  pooled[b * 256 + d] = s / fmaxf(c, 1.f);
}

// ---------------- projection GEMV: pe[b][r] = pooled[b] . proj_w[r] + proj_b[r] ----
__global__ __launch_bounds__(256) void proj_kernel(const float* __restrict__ pooled,
    const float* __restrict__ W, const float* __restrict__ bias, float* __restrict__ pe) {
  __shared__ float pl[1024];
  int t = threadIdx.x;
  for (int i = t; i < 1024; i += 256) pl[i] = pooled[i];
  __syncthreads();
  int wave = t >> 6, lane = t & 63;
  int half = lane >> 5, sl = lane & 31;
  int row = blockIdx.x * 8 + wave * 2 + half;
  float4 w0 = *(const float4*)(W + (size_t)row * 256 + sl * 8);
  float4 w1 = *(const float4*)(W + (size_t)row * 256 + sl * 8 + 4);
  float a0, a1, a2, a3;
#pragma unroll
  for (int bb = 0; bb < 4; ++bb) {
    const float* pp = &pl[bb * 256 + sl * 8];
    float v = w0.x * pp[0] + w0.y * pp[1] + w0.z * pp[2] + w0.w * pp[3]
            + w1.x * pp[4] + w1.y * pp[5] + w1.z * pp[6] + w1.w * pp[7];
    if (bb == 0) a0 = v; else if (bb == 1) a1 = v; else if (bb == 2) a2 = v; else a3 = v;
  }
#pragma unroll
  for (int off = 1; off < 32; off <<= 1) {
    a0 += __shfl_xor(a0, off); a1 += __shfl_xor(a1, off);
    a2 += __shfl_xor(a2, off); a3 += __shfl_xor(a3, off);
  }
  if (sl == 0) {
    float bv = bias[row];
    pe[0 * 114688 + row] = a0 + bv;
    pe[1 * 114688 + row] = a1 + bv;
    pe[2 * 114688 + row] = a2 + bv;
    pe[3 * 114688 + row] = a3 + bv;
  }
}

// ---------------- tile_A: out[b,i,r,c] = Abase[b,p(i),r,c&63] * sa[p] (fp32 out) ----
__global__ __launch_bounds__(256) void tile_a_kernel(const float* __restrict__ Abase,
    const float* __restrict__ scales, float* __restrict__ out, int nI, int ind,
    int pdiv, int pmul, int padd) {
  int row = blockIdx.x;                 // ((b*nI+i)*16 + r)
  int r = row & 15, bi = row >> 4;
  int i = bi % nI, b = bi / nI;
  int p = (i / pdiv) * 7 + (i % pdiv) * pmul + padd;
  float s = scales[2 * p];
  __shared__ float chunk[64];
  int t = threadIdx.x;
  if (t < 64) chunk[t] = Abase[((size_t)(b * 224 + p) * 16 + r) * 64 + t] * s;
  __syncthreads();
  size_t ob = (size_t)row * ind;
  for (int u = t; u * 4 < ind; u += 256) {
    int c0 = u * 4;
    float4 ov = *(const float4*)&chunk[c0 & 63];
    *(float4*)(out + ob + c0) = ov;
  }
}

// ---------------- tile_B: out[b,i,c,r] = Bbase[b,p(i),c&63,r] * sb[p] (fp32 out) ----
__global__ __launch_bounds__(256) void tile_b_kernel(const float* __restrict__ Bbase,
    const float* __restrict__ scales, float* __restrict__ out, int nI, int ind, int nchunks,
    int pdiv, int pmul, int padd) {
  int blk = blockIdx.x;
  int cc = blk % nchunks, bi = blk / nchunks;
  int i = bi % nI, b = bi / nI;
  int p = (i / pdiv) * 7 + (i % pdiv) * pmul + padd;
  float s = scales[2 * p + 1];
  __shared__ float chunk[1024];
  int t = threadIdx.x;
  for (int e = t; e < 1024; e += 256) chunk[e] = Bbase[(size_t)(b * 224 + p) * 1024 + e] * s;
  __syncthreads();
  int cchunk16 = (ind / nchunks) * 16;
  size_t ob = (size_t)bi * ind * 16 + (size_t)cc * cchunk16;
  for (int u = t; u * 4 < cchunk16; u += 256) {
    int e0 = u * 4;
    int cabs = (cc * cchunk16 + e0) >> 4;
    int src = ((cabs & 63) << 4) + (e0 & 15);
    float4 ov = *(const float4*)&chunk[src];
    *(float4*)(out + ob + e0) = ov;
  }
}

extern "C" void kernel_launch(void* const* d_in, const int* in_sizes, int n_in,
                              void* d_out, int out_size, void* d_ws, size_t ws_size,
                              hipStream_t stream) {
  const int* ids     = (const int*)d_in[0];
  const int* mask    = (const int*)d_in[1];
  const float* emb   = (const float*)d_in[2];
  const float* qkv_w = (const float*)d_in[3];
  const float* qkv_b = (const float*)d_in[4];
  const float* out_w = (const float*)d_in[5];
  const float* out_b = (const float*)d_in[6];
  const float* ln1_g = (const float*)d_in[7];
  const float* ln1_b = (const float*)d_in[8];
  const float* ff1_w = (const float*)d_in[9];
  const float* ff1_b = (const float*)d_in[10];
  const float* ff2_w = (const float*)d_in[11];
  const float* ff2_b = (const float*)d_in[12];
  const float* ln2_g = (const float*)d_in[13];
  const float* ln2_b = (const float*)d_in[14];
  const float* proj_w = (const float*)d_in[15];
  const float* proj_b = (const float*)d_in[16];
  const float* a1_w = (const float*)d_in[17];
  const float* a1_b = (const float*)d_in[18];
  const float* a2_w = (const float*)d_in[19];
  const float* a2_b = (const float*)d_in[20];
  const float* b1_w = (const float*)d_in[21];
  const float* b1_b = (const float*)d_in[22];
  const float* b2_w = (const float*)d_in[23];
  const float* b2_b = (const float*)d_in[24];
  const float* scales = (const float*)d_in[25];

  float* w = (float*)d_ws;
  float* x      = w + 0;        // 512*256
  float* qkv    = w + 262144;   // 512*768
  float* attn_o = w + 655360;   // 512*256
  float* ff     = w + 786432;   // 512*2048 (encoder); reused as decoder partsB
  float* pooled = w + 1835008;  // 4*256
  float* pe     = w + 1836032;  // 896*512
  float* hbuf   = w + 2294784;  // 896*512 fused: [:,0:256]=hA, [:,256:512]=hB
  float* Abase  = w + 2753536;  // 896*1024
  float* Bbase  = w + 3671040;  // 896*1024
  float* parts  = w + 4588544;  // up to 8*131072 enc / 4*229376 dec-A (scratch)

  float* out = (float*)d_out;
  const int NSB = 1 << 30;      // "never dual" sentinel

  embed_kernel<<<512, 256, 0, stream>>>(ids, emb, x);
  for (int l = 0; l < 3; ++l) {
    mfma_gemm_kernel<0, 0><<<dim3(8, 12), 256, 0, stream>>>(
        x, 256, qkv_w + l * 768 * 256, nullptr, NSB, 0, qkv_b + l * 768, nullptr,
        qkv, nullptr, 768, 256, 256, 0);
    attn_kernel<<<512, 256, 0, stream>>>(qkv, mask, attn_o);
    mfma_gemm_kernel<0, 1><<<dim3(8, 4, 4), 256, 0, stream>>>(
        attn_o, 256, out_w + l * 256 * 256, nullptr, NSB, 0, nullptr, nullptr,
        parts, nullptr, 256, 256, 64, 131072);
    add_ln_red_kernel<<<512, 256, 0, stream>>>(x, parts, 4, 131072, out_b + l * 256,
                                               ln1_g + l * 256, ln1_b + l * 256);
    mfma_gemm_kernel<1, 0><<<dim3(8, 32), 256, 0, stream>>>(
        x, 256, ff1_w + l * 2048 * 256, nullptr, NSB, 0, ff1_b + l * 2048, nullptr,
        ff, nullptr, 2048, 256, 256, 0);
    mfma_gemm_kernel<0, 1><<<dim3(8, 4, 8), 256, 0, stream>>>(
        ff, 2048, ff2_w + l * 256 * 2048, nullptr, NSB, 0, nullptr, nullptr,
        parts, nullptr, 256, 2048, 256, 131072);
    add_ln_red_kernel<<<512, 256, 0, stream>>>(x, parts, 8, 131072, ff2_b + l * 256,
                                               ln2_g + l * 256, ln2_b + l * 256);
  }
  pool_kernel<<<4, 256, 0, stream>>>(x, mask, pooled);
  proj_kernel<<<14336, 256, 0, stream>>>(pooled, proj_w, proj_b, pe);

  // ---- decoder A/B chains fused: 3 launches instead of 6 ----
  // stage1 dual split-K: y<4 -> A half (a1_w -> parts), y>=4 -> B half (b1_w -> ff)
  mfma_gemm_kernel<0, 1><<<dim3(14, 8, 4), 256, 0, stream>>>(
      pe, 512, a1_w, b1_w, 256, 0, nullptr, nullptr,
      parts, ff, 256, 512, 128, 229376);
  red_gelu_dual_kernel<<<1792, 256, 0, stream>>>(parts, ff, a1_b, b1_b, hbuf);
  // stage2 dual: y<16 -> Abase = hA @ a2_w^T, y>=16 -> Bbase = hB @ b2_w^T
  mfma_gemm_kernel<0, 0><<<dim3(14, 32), 256, 0, stream>>>(
      hbuf, 512, a2_w, b2_w, 1024, 256, a2_b, b2_b,
      Abase, Bbase, 1024, 256, 256, 0);

  // outputs (flat offsets in elements):
  // out0 A_HID (4,192,16,4096)  @ 0
  // out1 A_INT (4, 32,16,11008) @ 50331648
  // out2 B_HID (4, 96,4096,16)  @ 72876032
  // out3 B_KV  (4, 64,1024,16)  @ 98041856
  // out4 B_INT (4, 64,11008,16) @ 102236160
  tile_a_kernel<<<12288, 256, 0, stream>>>(Abase, scales, out, 192, 4096, 6, 1, 0);
  tile_a_kernel<<<2048, 256, 0, stream>>>(Abase, scales, out + 50331648ull, 32, 11008, 1, 0, 6);
  tile_b_kernel<<<3072, 256, 0, stream>>>(Bbase, scales, out + 72876032ull, 96, 4096, 8, 3, 3, 0);
  tile_b_kernel<<<512, 256, 0, stream>>>(Bbase, scales, out + 98041856ull, 64, 1024, 2, 2, 1, 1);
  tile_b_kernel<<<2048, 256, 0, stream>>>(Bbase, scales, out + 102236160ull, 64, 11008, 8, 2, 1, 4);
}

// Round 2
// 916.168 us; speedup vs baseline: 1.0656x; 1.0061x over previous
//
#include <hip/hip_runtime.h>
#include <hip/hip_bf16.h>

typedef unsigned short u16;
typedef unsigned int u32;
typedef __attribute__((ext_vector_type(8))) short short8;
typedef __attribute__((ext_vector_type(4))) float floatx4;

__device__ __forceinline__ u16 f2bf(float f) {
  u32 x = __float_as_uint(f);
  x += 0x7FFFu + ((x >> 16) & 1u);
  return (u16)(x >> 16);
}
__device__ __forceinline__ u32 pk2(float lo, float hi) {
  return (u32)f2bf(lo) | ((u32)f2bf(hi) << 16);
}

// ---------------- embedding gather: x[tok][d] = emb[ids[tok]][d] ----
__global__ void embed_kernel(const int* __restrict__ ids, const float* __restrict__ emb,
                             float* __restrict__ x) {
  int tok = blockIdx.x, d = threadIdx.x;
  x[tok * 256 + d] = emb[(size_t)ids[tok] * 256 + d];
}

// ---------------- bf16 MFMA GEMM: C = act(A[M,K] @ W[N,K]^T + bias) ------------
// block 256 (4 waves), tile 64x64. K staged in 128-wide chunks (CHUNK=128):
// A-tile 64x128 + W-tile 64x128 bf16 = 32 KB LDS, ONE barrier pair per phase.
// K=256 GEMMs: 2 phases / 3 barriers (was 8 phases / 8 barriers). Phase-2 global
// loads are register-prefetched under phase-1 MFMA.
// LDS layout: row-major [64][CHUNK] bf16 with granule XOR swizzle: 16B-granule g
// of row r stored at g ^ (r&7). Row stride 256B would otherwise be a 16-way bank
// conflict on ds_read_b128 (G4); swizzle applied identically on write and read.
// SPLIT=1: write partial sums to C + kz*pstride (no bias/act).
// DUAL: n-tiles with n0 >= nsplit switch to {Wb, biasb, Cb, A+koffb} so two
// independent GEMMs sharing M/K geometry run in one launch (decoder A/B merge).
// A-frag: lane holds A[m=lane&15][k=(lane>>4)*8+j]; B-frag same pattern on W.
// C/D: col=lane&15, row=(lane>>4)*4+reg  [guide §3, m89/m91].
template <int ACT, int SPLIT>
__global__ __launch_bounds__(256) void mfma_gemm_kernel(
    const float* __restrict__ A, int lda,
    const float* __restrict__ Wa, const float* __restrict__ Wb, int nsplit, int koffb,
    const float* __restrict__ biasa, const float* __restrict__ biasb,
    float* __restrict__ Ca, float* __restrict__ Cb,
    int N, int K, int KS, int pstride) {
  constexpr int CHUNK = 128;
  constexpr int NF4 = CHUNK / 16;          // float4 loads per operand per thread (8)
  __shared__ u16 Abf[64 * CHUNK];
  __shared__ u16 Wbf[64 * CHUNK];
  const int t = threadIdx.x;
  const int m0 = blockIdx.x * 64;
  int n0 = blockIdx.y * 64;
  const int kz = blockIdx.z;
  const float* W = Wa;
  const float* bias = biasa;
  const float* Ain = A;
  float* C = Ca;
  if (n0 >= nsplit) { n0 -= nsplit; W = Wb; bias = biasb; C = Cb; Ain = A + koffb; }
  const int srow = t >> 2, skc = (t & 3) * (CHUNK / 4);  // staging: 4 thr/row, 32 floats ea
  const int sr7 = srow & 7;
  const int g0 = skc >> 3;                 // starting 16B granule within row
  const int w = t >> 6, lane = t & 63;
  const int q = lane >> 4, rr = lane & 15;
  const int r7 = rr & 7;                   // read-side swizzle key (row&7 == rr&7)
  floatx4 acc[4];
#pragma unroll
  for (int i = 0; i < 4; ++i) acc[i] = (floatx4){0.f, 0.f, 0.f, 0.f};

  const int kbeg = kz * KS, kend = kbeg + KS;
  const float* ga = Ain + (size_t)(m0 + srow) * lda + kbeg + skc;
  const float* gw = W + (size_t)(n0 + srow) * K + kbeg + skc;
  float4 ar[NF4], wr[NF4];
#pragma unroll
  for (int j = 0; j < NF4; ++j) {
    ar[j] = *(const float4*)(ga + 4 * j);
    wr[j] = *(const float4*)(gw + 4 * j);
  }
  for (int kc = kbeg; kc < kend; kc += CHUNK) {
    if (kc != kbeg) __syncthreads();       // previous phase's LDS reads complete
#pragma unroll
    for (int j = 0; j < NF4 / 2; ++j) {    // pack 2 float4 -> one 16B bf16 granule
      uint4 pa, pw;
      pa.x = pk2(ar[2 * j].x, ar[2 * j].y);     pa.y = pk2(ar[2 * j].z, ar[2 * j].w);
      pa.z = pk2(ar[2 * j + 1].x, ar[2 * j + 1].y); pa.w = pk2(ar[2 * j + 1].z, ar[2 * j + 1].w);
      pw.x = pk2(wr[2 * j].x, wr[2 * j].y);     pw.y = pk2(wr[2 * j].z, wr[2 * j].w);
      pw.z = pk2(wr[2 * j + 1].x, wr[2 * j + 1].y); pw.w = pk2(wr[2 * j + 1].z, wr[2 * j + 1].w);
      int gs = (g0 + j) ^ sr7;
      *(uint4*)&Abf[srow * CHUNK + (gs << 3)] = pa;
      *(uint4*)&Wbf[srow * CHUNK + (gs << 3)] = pw;
    }
    if (kc + CHUNK < kend) {               // prefetch next phase under this phase's MFMA
      ga += CHUNK; gw += CHUNK;
#pragma unroll
      for (int j = 0; j < NF4; ++j) {
        ar[j] = *(const float4*)(ga + 4 * j);
        wr[j] = *(const float4*)(gw + 4 * j);
      }
    }
    __syncthreads();
#pragma unroll
    for (int ks = 0; ks < CHUNK / 32; ++ks) {
      int gA = ks * 4 + q;                 // granule holding k = ks*32 + q*8
      short8 af = *(short8*)&Abf[(w * 16 + rr) * CHUNK + (((gA ^ r7)) << 3)];
#pragma unroll
      for (int ct = 0; ct < 4; ++ct) {
        short8 bfv = *(short8*)&Wbf[(ct * 16 + rr) * CHUNK + (((gA ^ r7)) << 3)];
        acc[ct] = __builtin_amdgcn_mfma_f32_16x16x32_bf16(af, bfv, acc[ct], 0, 0, 0);
      }
    }
  }

  float* dst = SPLIT ? (C + (size_t)kz * pstride) : C;
#pragma unroll
  for (int ct = 0; ct < 4; ++ct) {
    int col = n0 + ct * 16 + rr;
#pragma unroll
    for (int r = 0; r < 4; ++r) {
      int row = m0 + w * 16 + q * 4 + r;
      float v = acc[ct][r];
      if (!SPLIT) {
        v += bias[col];
        if (ACT == 1) v = fmaxf(v, 0.f);
        if (ACT == 2) v = 0.5f * v * (1.f + erff(v * 0.70710678118654752f));
      }
      dst[(size_t)row * N + col] = v;
    }
  }
}

// ---------------- fused decoder stage-1 reduce: h[row][{A:0..255,B:256..511}] ----
__global__ __launch_bounds__(256) void red_gelu_dual_kernel(const float* __restrict__ pa,
    const float* __restrict__ pb, const float* __restrict__ ba, const float* __restrict__ bb,
    float* __restrict__ h) {
  int blk = blockIdx.x;
  int second = blk >= 896;
  int row = second ? blk - 896 : blk;
  const float* parts = second ? pb : pa;
  const float* bias = second ? bb : ba;
  int c = threadIdx.x;
  float v = bias[c];
#pragma unroll
  for (int p = 0; p < 4; ++p) v += parts[(size_t)p * 229376 + row * 256 + c];
  v = 0.5f * v * (1.f + erff(v * 0.70710678118654752f));
  h[(size_t)row * 512 + second * 256 + c] = v;
}

// ---------------- attention: one wave per query; K xor-swizzled in LDS ---------
// V is NOT staged: qkv (1.5 MB) is L2-resident and PV reads are lane-contiguous.
__global__ __launch_bounds__(256) void attn_kernel(const float* __restrict__ qkv,
    const int* __restrict__ mask, float* __restrict__ o) {
  __shared__ float Klds[8192];
  const int blk = blockIdx.x;                 // 512 = 4b * 4h * 32 qgroups
  const int b = blk >> 7, h = (blk >> 5) & 3, qg = blk & 31;
  const int t = threadIdx.x;
  for (int i = t; i < 8192; i += 256) {
    int s = i >> 6, d = i & 63;
    Klds[(s << 6) + (d ^ (s & 31))] = qkv[(size_t)(b * 128 + s) * 768 + h * 64 + 256 + d];
  }
  __syncthreads();
  const int wave = t >> 6, lane = t & 63;
  const int q = qg * 4 + wave;
  float qv = qkv[(size_t)(b * 128 + q) * 768 + h * 64 + lane];
  const int m0i = mask[b * 128 + lane];
  const int m1i = mask[b * 128 + 64 + lane];
  float s0 = 0.f, s1 = 0.f;
  const int sw = lane & 31;
  for (int d = 0; d < 64; ++d) {
    float qd = __shfl(qv, d);
    s0 += qd * Klds[(lane << 6) + (d ^ sw)];
    s1 += qd * Klds[((lane + 64) << 6) + (d ^ sw)];
  }
  s0 *= 0.125f; s1 *= 0.125f;
  if (m0i == 0) s0 = -1000000000.0f;
  if (m1i == 0) s1 = -1000000000.0f;
  float m = fmaxf(s0, s1);
  for (int off = 32; off; off >>= 1) m = fmaxf(m, __shfl_xor(m, off));
  float p0 = expf(s0 - m), p1 = expf(s1 - m);
  float sum = p0 + p1;
  for (int off = 32; off; off >>= 1) sum += __shfl_xor(sum, off);
  float rs = 1.f / sum;
  const float* vb = qkv + (size_t)b * 98304 + h * 64 + 512 + lane;
  float acc = 0.f;
#pragma unroll
  for (int k = 0; k < 64; ++k) acc += __shfl(p0, k) * vb[(size_t)k * 768];
#pragma unroll
  for (int k = 0; k < 64; ++k) acc += __shfl(p1, k) * vb[(size_t)(k + 64) * 768];
  o[(size_t)(b * 128 + q) * 256 + h * 64 + lane] = acc * rs;
}

// ---------------- residual + (optional bias) + split-K reduce + LayerNorm ----
__global__ __launch_bounds__(256) void add_ln_red_kernel(float* __restrict__ x,
    const float* __restrict__ parts, int nparts, int pstride, const float* __restrict__ bias,
    const float* __restrict__ g, const float* __restrict__ b) {
  int tok = blockIdx.x, t = threadIdx.x;
  int idx = tok * 256 + t;
  float r = x[idx] + (bias ? bias[t] : 0.f);
  for (int p = 0; p < nparts; ++p) r += parts[(size_t)p * pstride + idx];
  float s = r, sq = r * r;
  for (int off = 32; off; off >>= 1) { s += __shfl_xor(s, off); sq += __shfl_xor(sq, off); }
  __shared__ float red[8];
  int wave = t >> 6, lane = t & 63;
  if (lane == 0) { red[wave] = s; red[4 + wave] = sq; }
  __syncthreads();
  float S = red[0] + red[1] + red[2] + red[3];
  float SQ = red[4] + red[5] + red[6] + red[7];
  float mean = S * (1.f / 256.f);
  float var = SQ * (1.f / 256.f) - mean * mean;
  float inv = 1.f / sqrtf(fmaxf(var, 0.f) + 1e-5f);
  x[idx] = (r - mean) * inv * g[t] + b[t];
}

// ---------------- masked mean pool -> pooled[4][256] ----------------
__global__ void pool_kernel(const float* __restrict__ x, const int* __restrict__ mask,
                            float* __restrict__ pooled) {
  int b = blockIdx.x, d = threadIdx.x;
  float s = 0.f, c = 0.f;
  for (int ss = 0; ss < 128; ++ss) {
    float m = (float)mask[b * 128 + ss];
    s += m * x[(size_t)(b * 128 + ss) * 256 + d];
    c += m;
  }
  pooled[b * 256 + d] = s / fmaxf(c, 1.f);
}

// ---------------- projection GEMV: pe[b][r] = pooled[b] . proj_w[r] + proj_b[r] ----
__global__ __launch_bounds__(256) void proj_kernel(const float* __restrict__ pooled,
    const float* __restrict__ W, const float* __restrict__ bias, float* __restrict__ pe) {
  __shared__ float pl[1024];
  int t = threadIdx.x;
  for (int i = t; i < 1024; i += 256) pl[i] = pooled[i];
  __syncthreads();
  int wave = t >> 6, lane = t & 63;
  int half = lane >> 5, sl = lane & 31;
  int row = blockIdx.x * 8 + wave * 2 + half;
  float4 w0 = *(const float4*)(W + (size_t)row * 256 + sl * 8);
  float4 w1 = *(const float4*)(W + (size_t)row * 256 + sl * 8 + 4);
  float a0, a1, a2, a3;
#pragma unroll
  for (int bb = 0; bb < 4; ++bb) {
    const float* pp = &pl[bb * 256 + sl * 8];
    float v = w0.x * pp[0] + w0.y * pp[1] + w0.z * pp[2] + w0.w * pp[3]
            + w1.x * pp[4] + w1.y * pp[5] + w1.z * pp[6] + w1.w * pp[7];
    if (bb == 0) a0 = v; else if (bb == 1) a1 = v; else if (bb == 2) a2 = v; else a3 = v;
  }
#pragma unroll
  for (int off = 1; off < 32; off <<= 1) {
    a0 += __shfl_xor(a0, off); a1 += __shfl_xor(a1, off);
    a2 += __shfl_xor(a2, off); a3 += __shfl_xor(a3, off);
  }
  if (sl == 0) {
    float bv = bias[row];
    pe[0 * 114688 + row] = a0 + bv;
    pe[1 * 114688 + row] = a1 + bv;
    pe[2 * 114688 + row] = a2 + bv;
    pe[3 * 114688 + row] = a3 + bv;
  }
}

// ---------------- merged tiling: all 5 output expansions in ONE launch ----------
// removes 4 inter-kernel drain bubbles on the largest-traffic (589 MB) section.
__device__ __forceinline__ void tile_a_body(const float* __restrict__ Abase,
    const float* __restrict__ scales, float* __restrict__ out, int nI, int ind,
    int pdiv, int pmul, int padd, int row, int t, float* chunk) {
  int r = row & 15, bi = row >> 4;
  int i = bi % nI, b = bi / nI;
  int p = (i / pdiv) * 7 + (i % pdiv) * pmul + padd;
  float s = scales[2 * p];
  if (t < 64) chunk[t] = Abase[((size_t)(b * 224 + p) * 16 + r) * 64 + t] * s;
  __syncthreads();
  size_t ob = (size_t)row * ind;
  for (int u = t; u * 4 < ind; u += 256) {
    int c0 = u * 4;
    float4 ov = *(const float4*)&chunk[c0 & 63];
    *(float4*)(out + ob + c0) = ov;
  }
}

__device__ __forceinline__ void tile_b_body(const float* __restrict__ Bbase,
    const float* __restrict__ scales, float* __restrict__ out, int nI, int ind, int nchunks,
    int pdiv, int pmul, int padd, int blk, int t, float* chunk) {
  int cc = blk % nchunks, bi = blk / nchunks;
  int i = bi % nI, b = bi / nI;
  int p = (i / pdiv) * 7 + (i % pdiv) * pmul + padd;
  float s = scales[2 * p + 1];
  for (int e = t; e < 1024; e += 256) chunk[e] = Bbase[(size_t)(b * 224 + p) * 1024 + e] * s;
  __syncthreads();
  int cchunk16 = (ind / nchunks) * 16;
  size_t ob = (size_t)bi * ind * 16 + (size_t)cc * cchunk16;
  for (int u = t; u * 4 < cchunk16; u += 256) {
    int e0 = u * 4;
    int cabs = (cc * cchunk16 + e0) >> 4;
    int src = ((cabs & 63) << 4) + (e0 & 15);
    float4 ov = *(const float4*)&chunk[src];
    *(float4*)(out + ob + e0) = ov;
  }
}

// block ranges: [0,12288) A_HID | [12288,14336) A_INT | [14336,17408) B_HID |
//               [17408,17920) B_KV | [17920,19968) B_INT
__global__ __launch_bounds__(256) void tile_all_kernel(const float* __restrict__ Abase,
    const float* __restrict__ Bbase, const float* __restrict__ scales,
    float* __restrict__ out) {
  __shared__ float chunk[1024];
  int blk = blockIdx.x, t = threadIdx.x;
  if (blk < 12288) {
    tile_a_body(Abase, scales, out, 192, 4096, 6, 1, 0, blk, t, chunk);
  } else if (blk < 14336) {
    tile_a_body(Abase, scales, out + 50331648ull, 32, 11008, 1, 0, 6, blk - 12288, t, chunk);
  } else if (blk < 17408) {
    tile_b_body(Bbase, scales, out + 72876032ull, 96, 4096, 8, 3, 3, 0, blk - 14336, t, chunk);
  } else if (blk < 17920) {
    tile_b_body(Bbase, scales, out + 98041856ull, 64, 1024, 2, 2, 1, 1, blk - 17408, t, chunk);
  } else {
    tile_b_body(Bbase, scales, out + 102236160ull, 64, 11008, 8, 2, 1, 4, blk - 17920, t, chunk);
  }
}

extern "C" void kernel_launch(void* const* d_in, const int* in_sizes, int n_in,
                              void* d_out, int out_size, void* d_ws, size_t ws_size,
                              hipStream_t stream) {
  const int* ids     = (const int*)d_in[0];
  const int* mask    = (const int*)d_in[1];
  const float* emb   = (const float*)d_in[2];
  const float* qkv_w = (const float*)d_in[3];
  const float* qkv_b = (const float*)d_in[4];
  const float* out_w = (const float*)d_in[5];
  const float* out_b = (const float*)d_in[6];
  const float* ln1_g = (const float*)d_in[7];
  const float* ln1_b = (const float*)d_in[8];
  const float* ff1_w = (const float*)d_in[9];
  const float* ff1_b = (const float*)d_in[10];
  const float* ff2_w = (const float*)d_in[11];
  const float* ff2_b = (const float*)d_in[12];
  const float* ln2_g = (const float*)d_in[13];
  const float* ln2_b = (const float*)d_in[14];
  const float* proj_w = (const float*)d_in[15];
  const float* proj_b = (const float*)d_in[16];
  const float* a1_w = (const float*)d_in[17];
  const float* a1_b = (const float*)d_in[18];
  const float* a2_w = (const float*)d_in[19];
  const float* a2_b = (const float*)d_in[20];
  const float* b1_w = (const float*)d_in[21];
  const float* b1_b = (const float*)d_in[22];
  const float* b2_w = (const float*)d_in[23];
  const float* b2_b = (const float*)d_in[24];
  const float* scales = (const float*)d_in[25];

  float* w = (float*)d_ws;
  float* x      = w + 0;        // 512*256
  float* qkv    = w + 262144;   // 512*768
  float* attn_o = w + 655360;   // 512*256
  float* ff     = w + 786432;   // 512*2048 (encoder); reused as decoder partsB
  float* pooled = w + 1835008;  // 4*256
  float* pe     = w + 1836032;  // 896*512
  float* hbuf   = w + 2294784;  // 896*512 fused: [:,0:256]=hA, [:,256:512]=hB
  float* Abase  = w + 2753536;  // 896*1024
  float* Bbase  = w + 3671040;  // 896*1024
  float* parts  = w + 4588544;  // up to 8*131072 enc / 4*229376 dec-A (scratch)

  float* out = (float*)d_out;
  const int NSB = 1 << 30;      // "never dual" sentinel

  embed_kernel<<<512, 256, 0, stream>>>(ids, emb, x);
  for (int l = 0; l < 3; ++l) {
    // qkv: M=512 N=768 K=256 -> 2 phases
    mfma_gemm_kernel<0, 0><<<dim3(8, 12), 256, 0, stream>>>(
        x, 256, qkv_w + l * 768 * 256, nullptr, NSB, 0, qkv_b + l * 768, nullptr,
        qkv, nullptr, 768, 256, 256, 0);
    attn_kernel<<<512, 256, 0, stream>>>(qkv, mask, attn_o);
    // out-proj: non-split, bias fused -> parts holds biased GEMM result (1 part)
    mfma_gemm_kernel<0, 0><<<dim3(8, 4), 256, 0, stream>>>(
        attn_o, 256, out_w + l * 256 * 256, nullptr, NSB, 0, out_b + l * 256, nullptr,
        parts, nullptr, 256, 256, 256, 0);
    add_ln_red_kernel<<<512, 256, 0, stream>>>(x, parts, 1, 0, nullptr,
                                               ln1_g + l * 256, ln1_b + l * 256);
    mfma_gemm_kernel<1, 0><<<dim3(8, 32), 256, 0, stream>>>(
        x, 256, ff1_w + l * 2048 * 256, nullptr, NSB, 0, ff1_b + l * 2048, nullptr,
        ff, nullptr, 2048, 256, 256, 0);
    mfma_gemm_kernel<0, 1><<<dim3(8, 4, 8), 256, 0, stream>>>(
        ff, 2048, ff2_w + l * 256 * 2048, nullptr, NSB, 0, nullptr, nullptr,
        parts, nullptr, 256, 2048, 256, 131072);
    add_ln_red_kernel<<<512, 256, 0, stream>>>(x, parts, 8, 131072, ff2_b + l * 256,
                                               ln2_g + l * 256, ln2_b + l * 256);
  }
  pool_kernel<<<4, 256, 0, stream>>>(x, mask, pooled);
  proj_kernel<<<14336, 256, 0, stream>>>(pooled, proj_w, proj_b, pe);

  // ---- decoder A/B chains fused: 3 launches ----
  // stage1 dual split-K: y<4 -> A half (a1_w -> parts), y>=4 -> B half (b1_w -> ff)
  mfma_gemm_kernel<0, 1><<<dim3(14, 8, 4), 256, 0, stream>>>(
      pe, 512, a1_w, b1_w, 256, 0, nullptr, nullptr,
      parts, ff, 256, 512, 128, 229376);
  red_gelu_dual_kernel<<<1792, 256, 0, stream>>>(parts, ff, a1_b, b1_b, hbuf);
  // stage2 dual: y<16 -> Abase = hA @ a2_w^T, y>=16 -> Bbase = hB @ b2_w^T
  mfma_gemm_kernel<0, 0><<<dim3(14, 32), 256, 0, stream>>>(
      hbuf, 512, a2_w, b2_w, 1024, 256, a2_b, b2_b,
      Abase, Bbase, 1024, 256, 256, 0);

  // outputs (flat offsets in elements):
  // out0 A_HID (4,192,16,4096)  @ 0
  // out1 A_INT (4, 32,16,11008) @ 50331648
  // out2 B_HID (4, 96,4096,16)  @ 72876032
  // out3 B_KV  (4, 64,1024,16)  @ 98041856
  // out4 B_INT (4, 64,11008,16) @ 102236160
  tile_all_kernel<<<19968, 256, 0, stream>>>(Abase, Bbase, scales, out);
}